// Round 8
// baseline (115.993 us; speedup 1.0000x reference)
//
#include <hip/hip_runtime.h>

#define D_MODEL 256
#define N_HEADS 8
#define MAXN 128    // max neighbors/row; Poisson(32): P(row>128) ~ 1e-40
#define NGEMM 384   // 3 z * 32 by * 4 bx

typedef __attribute__((ext_vector_type(8))) short bf16x8;
typedef __attribute__((ext_vector_type(4))) float f32x4;

// wave-local LDS fence: order DS ops within this wave (private LDS slice)
#define WSYNC() asm volatile("s_waitcnt lgkmcnt(0)" ::: "memory")

__device__ __forceinline__ unsigned short f2bf(float f) {
    union { float f; unsigned int u; } v; v.f = f;
    unsigned int r = v.u + 0x7fff + ((v.u >> 16) & 1);   // RNE
    return (unsigned short)(r >> 16);
}
__device__ __forceinline__ float bf2f(unsigned short u) {
    union { unsigned int u; float f; } v; v.u = ((unsigned int)u) << 16;
    return v.f;
}

// ---------------------------------------------------------------------------
// prep: fp32->bf16 converts (x + 4 weights) AND mask init (zeros + diagonal).
// ---------------------------------------------------------------------------
__global__ void prep_kernel(const float* __restrict__ x,
                            const float* __restrict__ W0, const float* __restrict__ W1,
                            const float* __restrict__ W2, const float* __restrict__ W3,
                            unsigned short* __restrict__ xb,
                            unsigned short* __restrict__ O0, unsigned short* __restrict__ O1,
                            unsigned short* __restrict__ O2, unsigned short* __restrict__ O3,
                            unsigned long long* __restrict__ mask, int n) {
    const int XV = (4096 * 256) / 4;          // 262144 float4s of x
    int i = blockIdx.x * blockDim.x + threadIdx.x;

    int wpr = n >> 6;
    int mwords = n * wpr;
    if (i < mwords) {
        int row = i >> 6;                     // wpr == 64
        int w = i & 63;
        mask[i] = (w == (row >> 6)) ? (1ULL << (row & 63)) : 0ULL;
    }

    const float* src;
    unsigned short* dst;
    int k;
    if (i < XV) {
        src = x; dst = xb; k = i;
    } else {
        int i2 = i - XV;                      // < 4*16384
        if (i2 >= 4 * 16384) return;
        int z = i2 >> 14;
        k = i2 & 16383;
        src = (z == 0) ? W0 : (z == 1) ? W1 : (z == 2) ? W2 : W3;
        dst = (z == 0) ? O0 : (z == 1) ? O1 : (z == 2) ? O2 : O3;
    }
    float4 v = *(const float4*)(src + (size_t)k * 4);
    ushort4 o;
    o.x = f2bf(v.x); o.y = f2bf(v.y); o.z = f2bf(v.z); o.w = f2bf(v.w);
    *(ushort4*)(dst + (size_t)k * 4) = o;
}

// ---------------------------------------------------------------------------
// Fused: QKV GEMM (blocks 0..NGEMM-1) + edge-mask atomicOr (blocks NGEMM..).
// GEMM: C = xb @ W^T (bf16 in/out). BM=128, BN=64, BK=128 (2 k-iters, half
// the barriers of BK=64). 256 thr = 4 waves, each 64x32 (4x2 MFMA tiles).
// ---------------------------------------------------------------------------
__global__ __launch_bounds__(256) void qkv_edges_kernel(
        const unsigned short* __restrict__ xb,
        const unsigned short* __restrict__ Wq, const unsigned short* __restrict__ Wk,
        const unsigned short* __restrict__ Wv,
        unsigned short* __restrict__ Qb, unsigned short* __restrict__ Kb,
        unsigned short* __restrict__ Vb,
        const int* __restrict__ ei, unsigned long long* __restrict__ mask,
        int E, int n) {
    int blk = blockIdx.x;
    if (blk >= NGEMM) {
        int e = (blk - NGEMM) * 256 + threadIdx.x;
        if (e < E) {
            int src = ei[e];
            int dst = ei[E + e];
            int wpr = n >> 6;
            atomicOr(&mask[(size_t)dst * wpr + (src >> 6)], 1ULL << (src & 63));
        }
        return;
    }
    int z = blk >> 7;
    int r = blk & 127;
    int by = r >> 2, bx = r & 3;
    const unsigned short* B = (z == 0) ? Wq : (z == 1) ? Wk : Wv;
    unsigned short* Cb = (z == 0) ? Qb : (z == 1) ? Kb : Vb;

    __shared__ short Alds[128][136];   // +8 pad (272B row stride)
    __shared__ short Blds[64][136];
    int t = threadIdx.x;
    int wave = t >> 6, lane = t & 63;
    int wr = wave >> 1, wc = wave & 1;
    int lrA = t >> 4;             // 0..15
    int lc = (t & 15) << 3;       // 0..120 (8 bf16 = 16B chunks)

    int fm = lane & 15;
    int fk = (lane >> 4) << 3;

    f32x4 acc[4][2];
#pragma unroll
    for (int rr = 0; rr < 4; ++rr)
#pragma unroll
        for (int c = 0; c < 2; ++c) acc[rr][c] = (f32x4){0.f, 0.f, 0.f, 0.f};

    for (int k0 = 0; k0 < D_MODEL; k0 += 128) {
#pragma unroll
        for (int i = 0; i < 8; ++i)
            *(uint4*)&Alds[lrA + 16 * i][lc] =
                *(const uint4*)(xb + ((size_t)(by * 128 + lrA + 16 * i)) * D_MODEL + k0 + lc);
#pragma unroll
        for (int i = 0; i < 4; ++i)
            *(uint4*)&Blds[lrA + 16 * i][lc] =
                *(const uint4*)(B + ((size_t)(bx * 64 + lrA + 16 * i)) * D_MODEL + k0 + lc);
        __syncthreads();
#pragma unroll
        for (int ks = 0; ks < 128; ks += 32) {
            bf16x8 af[4], bf[2];
#pragma unroll
            for (int rr = 0; rr < 4; ++rr)
                af[rr] = *(const bf16x8*)&Alds[wr * 64 + rr * 16 + fm][ks + fk];
#pragma unroll
            for (int c = 0; c < 2; ++c)
                bf[c] = *(const bf16x8*)&Blds[wc * 32 + c * 16 + fm][ks + fk];
#pragma unroll
            for (int rr = 0; rr < 4; ++rr)
#pragma unroll
                for (int c = 0; c < 2; ++c)
                    acc[rr][c] = __builtin_amdgcn_mfma_f32_16x16x32_bf16(
                        af[rr], bf[c], acc[rr][c], 0, 0, 0);
        }
        __syncthreads();
    }

    int orow0 = by * 128 + wr * 64 + ((lane >> 4) << 2);
    int ocol0 = bx * 64 + wc * 32 + (lane & 15);
#pragma unroll
    for (int rr = 0; rr < 4; ++rr)
#pragma unroll
        for (int c = 0; c < 2; ++c)
#pragma unroll
            for (int q = 0; q < 4; ++q)
                Cb[(size_t)(orow0 + rr * 16 + q) * D_MODEL + ocol0 + c * 16] =
                    f2bf(acc[rr][c][q]);
}

// ---------------------------------------------------------------------------
// Sparse attention, two-pass, MFMA-scored. 4 waves/block, one dst per wave,
// private LDS slices, wave-local fences. ILP-tuned:
//  - Phase B: 4 independent MFMA chains (dep depth 2), hoisted K loads.
//  - Phase D: half-wave 16B V gathers (full row per instr), 8-nbr unroll,
//    shfl_xor(32) combine.
// ---------------------------------------------------------------------------
__global__ __launch_bounds__(256, 4) void attn_kernel(
        const unsigned short* __restrict__ Qb, const unsigned short* __restrict__ Kb,
        const unsigned short* __restrict__ Vb,
        const unsigned long long* __restrict__ mask,
        unsigned short* __restrict__ Ob, int n) {
    __shared__ int nbr_s[4][MAXN + 16];
    __shared__ float s_s[4][N_HEADS][MAXN];
    __shared__ float lsum_s[4][N_HEADS];

    int t = threadIdx.x;
    int wave = t >> 6, L = t & 63;
    int wpr = n >> 6;
    int dst = blockIdx.x * 4 + wave;

    int* nbrw = nbr_s[wave];
    float (*sw)[MAXN] = s_s[wave];

    // ---- Phase A: neighbor enumeration ----
    unsigned long long w = (L < wpr) ? mask[(size_t)dst * wpr + L] : 0ULL;
    int c = __popcll(w);
    int xs = c;
#pragma unroll
    for (int o = 1; o < 64; o <<= 1) {
        int y = __shfl_up(xs, o, 64);
        if (L >= o) xs += y;
    }
    int pos = xs - c;
    while (w) {
        int b = __builtin_ctzll(w);
        w &= w - 1;
        if (pos < MAXN) nbrw[pos] = (L << 6) + b;
        ++pos;
    }
    int cnt = __shfl(xs, 63, 64);
    if (cnt > MAXN) cnt = MAXN;
    int nb = (cnt + 15) & ~15;
    WSYNC();
    int last = nbrw[cnt - 1];
    if (L < nb - cnt) nbrw[cnt + L] = last;   // pad; padded scores forced to -1e30
    WSYNC();

    // per-lane Q fragment (col = head for col<8, else zero)
    int col = L & 15;
    int kq = L >> 4;
    bf16x8 qf = (bf16x8){0, 0, 0, 0, 0, 0, 0, 0};
    if (col < N_HEADS)
        qf = *(const bf16x8*)(Qb + (size_t)dst * D_MODEL + col * 32 + kq * 8);
    const bf16x8 zf = (bf16x8){0, 0, 0, 0, 0, 0, 0, 0};
    const float inv_scale = 0.17677669529663687f;   // 1/sqrt(32)

    // ---- Phase B: scores via MFMA (head-masked B trick), 4 acc chains ----
    for (int b0 = 0; b0 < nb; b0 += 16) {
        int nj = nbrw[b0 + col];
        const unsigned short* krow = Kb + (size_t)nj * D_MODEL + kq * 8;
        bf16x8 a[8];
#pragma unroll
        for (int kb = 0; kb < 8; ++kb)
            a[kb] = *(const bf16x8*)(krow + kb * 32);
        f32x4 c0 = (f32x4){0.f, 0.f, 0.f, 0.f};
        f32x4 c1 = (f32x4){0.f, 0.f, 0.f, 0.f};
        f32x4 c2 = (f32x4){0.f, 0.f, 0.f, 0.f};
        f32x4 c3 = (f32x4){0.f, 0.f, 0.f, 0.f};
        c0 = __builtin_amdgcn_mfma_f32_16x16x32_bf16(a[0], (col == 0) ? qf : zf, c0, 0, 0, 0);
        c1 = __builtin_amdgcn_mfma_f32_16x16x32_bf16(a[1], (col == 1) ? qf : zf, c1, 0, 0, 0);
        c2 = __builtin_amdgcn_mfma_f32_16x16x32_bf16(a[2], (col == 2) ? qf : zf, c2, 0, 0, 0);
        c3 = __builtin_amdgcn_mfma_f32_16x16x32_bf16(a[3], (col == 3) ? qf : zf, c3, 0, 0, 0);
        c0 = __builtin_amdgcn_mfma_f32_16x16x32_bf16(a[4], (col == 4) ? qf : zf, c0, 0, 0, 0);
        c1 = __builtin_amdgcn_mfma_f32_16x16x32_bf16(a[5], (col == 5) ? qf : zf, c1, 0, 0, 0);
        c2 = __builtin_amdgcn_mfma_f32_16x16x32_bf16(a[6], (col == 6) ? qf : zf, c2, 0, 0, 0);
        c3 = __builtin_amdgcn_mfma_f32_16x16x32_bf16(a[7], (col == 7) ? qf : zf, c3, 0, 0, 0);
        if (col < N_HEADS) {
            int jr = b0 + kq * 4;
            float4 o4;
            float s0 = ((c0[0] + c1[0]) + (c2[0] + c3[0])) * inv_scale;
            float s1 = ((c0[1] + c1[1]) + (c2[1] + c3[1])) * inv_scale;
            float s2 = ((c0[2] + c1[2]) + (c2[2] + c3[2])) * inv_scale;
            float s3 = ((c0[3] + c1[3]) + (c2[3] + c3[3])) * inv_scale;
            o4.x = (jr + 0 < cnt) ? s0 : -1e30f;
            o4.y = (jr + 1 < cnt) ? s1 : -1e30f;
            o4.z = (jr + 2 < cnt) ? s2 : -1e30f;
            o4.w = (jr + 3 < cnt) ? s3 : -1e30f;
            *(float4*)&sw[col][jr] = o4;
        }
    }
    WSYNC();

    // ---- Phase C: softmax (h = L>>3, 8 lanes per head) ----
    int h = L >> 3, li = L & 7;
    float m = -1e30f;
    for (int j0 = li * 4; j0 < nb; j0 += 32) {
        float4 v = *(const float4*)&sw[h][j0];
        m = fmaxf(m, fmaxf(fmaxf(v.x, v.y), fmaxf(v.z, v.w)));
    }
    m = fmaxf(m, __shfl_xor(m, 1, 8));
    m = fmaxf(m, __shfl_xor(m, 2, 8));
    m = fmaxf(m, __shfl_xor(m, 4, 8));
    float l = 0.f;
    for (int j0 = li * 4; j0 < nb; j0 += 32) {
        float4 v = *(const float4*)&sw[h][j0];
        float4 e4;
        e4.x = __expf(v.x - m); e4.y = __expf(v.y - m);
        e4.z = __expf(v.z - m); e4.w = __expf(v.w - m);
        *(float4*)&sw[h][j0] = e4;
        l += (e4.x + e4.y) + (e4.z + e4.w);
    }
    l += __shfl_xor(l, 1, 8);
    l += __shfl_xor(l, 2, 8);
    l += __shfl_xor(l, 4, 8);
    if (li == 0) lsum_s[wave][h] = l;
    WSYNC();

    // ---- Phase D: PV, half-wave 16B gathers. Lane covers dims 8*(L&31)..+7
    // of neighbors j+H (H = L>>5). Partner lane L^32 covers the other half. ----
    int H = L >> 5, l5 = L & 31;
    int hsel = l5 >> 2;                       // head of this lane's dims
    float rl = 1.f / lsum_s[wave][hsel];
    f32x4 accA = (f32x4){0.f, 0.f, 0.f, 0.f};
    f32x4 accB = (f32x4){0.f, 0.f, 0.f, 0.f};
    const unsigned short* vb = Vb + 8 * l5;
    for (int j = 0; j < nb; j += 8) {
        int j0 = nbrw[j + 0 + H], j1 = nbrw[j + 2 + H];
        int j2 = nbrw[j + 4 + H], j3 = nbrw[j + 6 + H];
        float w0 = sw[hsel][j + 0 + H], w1 = sw[hsel][j + 2 + H];
        float w2 = sw[hsel][j + 4 + H], w3 = sw[hsel][j + 6 + H];
        uint4 r0 = *(const uint4*)(vb + (size_t)j0 * D_MODEL);
        uint4 r1 = *(const uint4*)(vb + (size_t)j1 * D_MODEL);
        uint4 r2 = *(const uint4*)(vb + (size_t)j2 * D_MODEL);
        uint4 r3 = *(const uint4*)(vb + (size_t)j3 * D_MODEL);
#define ACC8(rr, ww) \
        accA[0] += ww * bf2f((unsigned short)(rr.x & 0xffff)); \
        accA[1] += ww * bf2f((unsigned short)(rr.x >> 16));    \
        accA[2] += ww * bf2f((unsigned short)(rr.y & 0xffff)); \
        accA[3] += ww * bf2f((unsigned short)(rr.y >> 16));    \
        accB[0] += ww * bf2f((unsigned short)(rr.z & 0xffff)); \
        accB[1] += ww * bf2f((unsigned short)(rr.z >> 16));    \
        accB[2] += ww * bf2f((unsigned short)(rr.w & 0xffff)); \
        accB[3] += ww * bf2f((unsigned short)(rr.w >> 16));
        ACC8(r0, w0) ACC8(r1, w1) ACC8(r2, w2) ACC8(r3, w3)
#undef ACC8
    }
    // combine halves: partner lane (L^32) holds same dims, other neighbors
#pragma unroll
    for (int q = 0; q < 4; ++q) {
        accA[q] = (accA[q] + __shfl_xor(accA[q], 32, 64)) * rl;
        accB[q] = (accB[q] + __shfl_xor(accB[q], 32, 64)) * rl;
    }
    if (H == 0) {
        ushort4 oa, ob;
        oa.x = f2bf(accA[0]); oa.y = f2bf(accA[1]);
        oa.z = f2bf(accA[2]); oa.w = f2bf(accA[3]);
        ob.x = f2bf(accB[0]); ob.y = f2bf(accB[1]);
        ob.z = f2bf(accB[2]); ob.w = f2bf(accB[3]);
        unsigned short* op = Ob + (size_t)dst * D_MODEL + 8 * l5;
        *(ushort4*)op = oa;
        *(ushort4*)(op + 4) = ob;
    }
}

// ---------------------------------------------------------------------------
// Fused output GEMM + residual + bias + LayerNorm.
// BM=16, BN=256 (full row), BK=64 -> 256 blocks (full CU coverage).
// 4 waves; wave w computes rows 0..15 x cols w*64..+63 (4 MFMA col-tiles).
// ---------------------------------------------------------------------------
struct SMemO {
    union {
        struct { short A[16][72]; short B[256][72]; } st;
        float c[16][260];
    };
};

__global__ __launch_bounds__(256) void gemm_o_ln_kernel(
        const unsigned short* __restrict__ Ob, const unsigned short* __restrict__ Wob,
        const float* __restrict__ x, const float* __restrict__ bo,
        const float* __restrict__ gamma, const float* __restrict__ beta,
        float* __restrict__ out) {
    __shared__ SMemO sm;
    int by = blockIdx.x;
    int t = threadIdx.x;
    int wave = t >> 6, lane = t & 63;
    int fm = lane & 15;
    int fk = (lane >> 4) << 3;

    int lrB = t >> 3;             // 0..31
    int lcB = (t & 7) << 3;       // 0..56
    int lrA = t >> 4;             // 0..15
    int lcA = (t & 15) << 2;      // 0..60 (uint2 = 4 bf16)

    f32x4 acc[4];
#pragma unroll
    for (int ct = 0; ct < 4; ++ct) acc[ct] = (f32x4){0.f, 0.f, 0.f, 0.f};

    for (int k0 = 0; k0 < D_MODEL; k0 += 64) {
        *(uint2*)&sm.st.A[lrA][lcA] =
            *(const uint2*)(Ob + ((size_t)(by * 16 + lrA)) * D_MODEL + k0 + lcA);
#pragma unroll
        for (int j = 0; j < 8; ++j)
            *(uint4*)&sm.st.B[lrB + 32 * j][lcB] =
                *(const uint4*)(Wob + ((size_t)(lrB + 32 * j)) * D_MODEL + k0 + lcB);
        __syncthreads();
#pragma unroll
        for (int ks = 0; ks < 64; ks += 32) {
            bf16x8 af = *(const bf16x8*)&sm.st.A[fm][ks + fk];
#pragma unroll
            for (int ct = 0; ct < 4; ++ct) {
                bf16x8 bf = *(const bf16x8*)&sm.st.B[wave * 64 + ct * 16 + fm][ks + fk];
                acc[ct] = __builtin_amdgcn_mfma_f32_16x16x32_bf16(af, bf, acc[ct], 0, 0, 0);
            }
        }
        __syncthreads();
    }

    int rr0 = (lane >> 4) << 2;
#pragma unroll
    for (int ct = 0; ct < 4; ++ct)
#pragma unroll
        for (int q = 0; q < 4; ++q)
            sm.c[rr0 + q][wave * 64 + ct * 16 + (lane & 15)] = acc[ct][q];
    __syncthreads();

    float4 bo4 = *(const float4*)(bo + lane * 4);
    float4 g4  = *(const float4*)(gamma + lane * 4);
    float4 be4 = *(const float4*)(beta + lane * 4);
#pragma unroll
    for (int rr = 0; rr < 4; ++rr) {
        int r = wave * 4 + rr;
        int grow = by * 16 + r;
        float4 p = *(const float4*)&sm.c[r][lane * 4];
        float4 xv = *(const float4*)(x + (size_t)grow * D_MODEL + lane * 4);
        float hx = p.x + xv.x + bo4.x;
        float hy = p.y + xv.y + bo4.y;
        float hz = p.z + xv.z + bo4.z;
        float hw = p.w + xv.w + bo4.w;
        float s  = (hx + hy) + (hz + hw);
        float s2 = (hx * hx + hy * hy) + (hz * hz + hw * hw);
#pragma unroll
        for (int o = 32; o; o >>= 1) {
            s  += __shfl_xor(s, o, 64);
            s2 += __shfl_xor(s2, o, 64);
        }
        float mu = s * (1.f / 256.f);
        float var = s2 * (1.f / 256.f) - mu * mu;
        float rstd = rsqrtf(var + 1e-5f);
        float4 o4;
        o4.x = (hx - mu) * rstd * g4.x + be4.x;
        o4.y = (hy - mu) * rstd * g4.y + be4.y;
        o4.z = (hz - mu) * rstd * g4.z + be4.z;
        o4.w = (hw - mu) * rstd * g4.w + be4.w;
        *(float4*)(out + (size_t)grow * D_MODEL + lane * 4) = o4;
    }
}

// ---------------------------------------------------------------------------
extern "C" void kernel_launch(void* const* d_in, const int* in_sizes, int n_in,
                              void* d_out, int out_size, void* d_ws, size_t ws_size,
                              hipStream_t stream) {
    const float* x     = (const float*)d_in[0];
    const int*   ei    = (const int*)  d_in[1];
    const float* Wq    = (const float*)d_in[2];
    const float* Wk    = (const float*)d_in[3];
    const float* Wv    = (const float*)d_in[4];
    const float* Wo    = (const float*)d_in[5];
    const float* bo    = (const float*)d_in[6];
    const float* gamma = (const float*)d_in[7];
    const float* beta  = (const float*)d_in[8];
    float* out = (float*)d_out;

    int n = in_sizes[0] / D_MODEL;   // 4096
    int E = in_sizes[1] / 2;         // 131072

    char* ws = (char*)d_ws;
    size_t off = 0;
    unsigned long long* mask = (unsigned long long*)(ws + off);
    off += (size_t)n * (n >> 6) * sizeof(unsigned long long);          // 2 MiB
    unsigned short* xb  = (unsigned short*)(ws + off); off += (size_t)n * D_MODEL * 2;
    unsigned short* Wqb = (unsigned short*)(ws + off); off += D_MODEL * D_MODEL * 2;
    unsigned short* Wkb = (unsigned short*)(ws + off); off += D_MODEL * D_MODEL * 2;
    unsigned short* Wvb = (unsigned short*)(ws + off); off += D_MODEL * D_MODEL * 2;
    unsigned short* Wob = (unsigned short*)(ws + off); off += D_MODEL * D_MODEL * 2;
    unsigned short* Qb  = (unsigned short*)(ws + off); off += (size_t)n * D_MODEL * 2;
    unsigned short* Kb  = (unsigned short*)(ws + off); off += (size_t)n * D_MODEL * 2;
    unsigned short* Vb  = (unsigned short*)(ws + off); off += (size_t)n * D_MODEL * 2;
    unsigned short* Ob  = (unsigned short*)(ws + off); off += (size_t)n * D_MODEL * 2;

    // 1) prep: converts + mask init (diag)
    prep_kernel<<<1280, 256, 0, stream>>>(x, Wq, Wk, Wv, Wo,
                                          xb, Wqb, Wkb, Wvb, Wob, mask, n);

    // 2) fused QKV GEMM + edge scatter
    int edge_blocks = (E + 255) / 256;       // 512
    qkv_edges_kernel<<<NGEMM + edge_blocks, 256, 0, stream>>>(
        xb, Wqb, Wkb, Wvb, Qb, Kb, Vb, ei, mask, E, n);

    // 3) sparse attention: 4 dsts per 256-thr block
    attn_kernel<<<n / 4, 256, 0, stream>>>(Qb, Kb, Vb, mask, Ob, n);

    // 4) output GEMM + residual + LayerNorm (256 blocks — full CU coverage)
    gemm_o_ln_kernel<<<n / 16, 256, 0, stream>>>(Ob, Wob, x, bo, gamma, beta, out);
}

// Round 9
// 112.875 us; speedup vs baseline: 1.0276x; 1.0276x over previous
//
#include <hip/hip_runtime.h>

#define D_MODEL 256
#define N_HEADS 8
#define MAXN 128    // max neighbors/row; Poisson(32): P(row>128) ~ 1e-40
#define NGEMM 384   // 3 z * 32 by * 4 bx

typedef __attribute__((ext_vector_type(8))) short bf16x8;
typedef __attribute__((ext_vector_type(4))) float f32x4;

__device__ __forceinline__ unsigned short f2bf(float f) {
    union { float f; unsigned int u; } v; v.f = f;
    unsigned int r = v.u + 0x7fff + ((v.u >> 16) & 1);   // RNE
    return (unsigned short)(r >> 16);
}
__device__ __forceinline__ float bf2f(unsigned short u) {
    union { unsigned int u; float f; } v; v.u = ((unsigned int)u) << 16;
    return v.f;
}

// ---------------------------------------------------------------------------
// prep: fp32->bf16 converts (x + 4 weights) AND mask init (zeros + diagonal).
// ---------------------------------------------------------------------------
__global__ void prep_kernel(const float* __restrict__ x,
                            const float* __restrict__ W0, const float* __restrict__ W1,
                            const float* __restrict__ W2, const float* __restrict__ W3,
                            unsigned short* __restrict__ xb,
                            unsigned short* __restrict__ O0, unsigned short* __restrict__ O1,
                            unsigned short* __restrict__ O2, unsigned short* __restrict__ O3,
                            unsigned long long* __restrict__ mask, int n) {
    const int XV = (4096 * 256) / 4;          // 262144 float4s of x
    int i = blockIdx.x * blockDim.x + threadIdx.x;

    int wpr = n >> 6;
    int mwords = n * wpr;
    if (i < mwords) {
        int row = i >> 6;                     // wpr == 64
        int w = i & 63;
        mask[i] = (w == (row >> 6)) ? (1ULL << (row & 63)) : 0ULL;
    }

    const float* src;
    unsigned short* dst;
    int k;
    if (i < XV) {
        src = x; dst = xb; k = i;
    } else {
        int i2 = i - XV;                      // < 4*16384
        if (i2 >= 4 * 16384) return;
        int z = i2 >> 14;
        k = i2 & 16383;
        src = (z == 0) ? W0 : (z == 1) ? W1 : (z == 2) ? W2 : W3;
        dst = (z == 0) ? O0 : (z == 1) ? O1 : (z == 2) ? O2 : O3;
    }
    float4 v = *(const float4*)(src + (size_t)k * 4);
    ushort4 o;
    o.x = f2bf(v.x); o.y = f2bf(v.y); o.z = f2bf(v.z); o.w = f2bf(v.w);
    *(ushort4*)(dst + (size_t)k * 4) = o;
}

// ---------------------------------------------------------------------------
// Fused: QKV GEMM (blocks 0..NGEMM-1) + edge-mask atomicOr (blocks NGEMM..).
// GEMM: C = xb @ W^T (bf16 in, bf16 out). BM=128, BN=64, BK=64.
// 28 KB LDS -> 4 blocks/CU (BK=128 variant measured worse: 52 KB -> 2-3/CU).
// ---------------------------------------------------------------------------
__global__ __launch_bounds__(256) void qkv_edges_kernel(
        const unsigned short* __restrict__ xb,
        const unsigned short* __restrict__ Wq, const unsigned short* __restrict__ Wk,
        const unsigned short* __restrict__ Wv,
        unsigned short* __restrict__ Qb, unsigned short* __restrict__ Kb,
        unsigned short* __restrict__ Vb,
        const int* __restrict__ ei, unsigned long long* __restrict__ mask,
        int E, int n) {
    int blk = blockIdx.x;
    if (blk >= NGEMM) {
        int e = (blk - NGEMM) * 256 + threadIdx.x;
        if (e < E) {
            int src = ei[e];
            int dst = ei[E + e];
            int wpr = n >> 6;
            atomicOr(&mask[(size_t)dst * wpr + (src >> 6)], 1ULL << (src & 63));
        }
        return;
    }
    int z = blk >> 7;
    int r = blk & 127;
    int by = r >> 2, bx = r & 3;
    const unsigned short* B = (z == 0) ? Wq : (z == 1) ? Wk : Wv;
    unsigned short* Cb = (z == 0) ? Qb : (z == 1) ? Kb : Vb;

    __shared__ short Alds[128][72];   // +8 pad
    __shared__ short Blds[64][72];
    int t = threadIdx.x;
    int wave = t >> 6, lane = t & 63;
    int wr = wave >> 1, wc = wave & 1;
    int lr = t >> 3;
    int lk = (t & 7) << 3;

    const unsigned short* Abase = xb + ((size_t)(by * 128 + lr)) * D_MODEL + lk;
    const unsigned short* Bbase = B + ((size_t)(bx * 64 + lr)) * D_MODEL + lk;

    int fm = lane & 15;
    int fk = (lane >> 4) << 3;

    f32x4 acc[4][2];
#pragma unroll
    for (int rr = 0; rr < 4; ++rr)
#pragma unroll
        for (int c = 0; c < 2; ++c) acc[rr][c] = (f32x4){0.f, 0.f, 0.f, 0.f};

    for (int k0 = 0; k0 < D_MODEL; k0 += 64) {
        *(uint4*)&Alds[lr][lk]      = *(const uint4*)(Abase + k0);
        *(uint4*)&Alds[lr + 32][lk] = *(const uint4*)(Abase + 32 * D_MODEL + k0);
        *(uint4*)&Alds[lr + 64][lk] = *(const uint4*)(Abase + 64 * D_MODEL + k0);
        *(uint4*)&Alds[lr + 96][lk] = *(const uint4*)(Abase + 96 * D_MODEL + k0);
        *(uint4*)&Blds[lr][lk]      = *(const uint4*)(Bbase + k0);
        *(uint4*)&Blds[lr + 32][lk] = *(const uint4*)(Bbase + 32 * D_MODEL + k0);
        __syncthreads();
#pragma unroll
        for (int ks = 0; ks < 64; ks += 32) {
            bf16x8 af[4], bf[2];
#pragma unroll
            for (int rr = 0; rr < 4; ++rr)
                af[rr] = *(const bf16x8*)&Alds[wr * 64 + rr * 16 + fm][ks + fk];
#pragma unroll
            for (int c = 0; c < 2; ++c)
                bf[c] = *(const bf16x8*)&Blds[wc * 32 + c * 16 + fm][ks + fk];
#pragma unroll
            for (int rr = 0; rr < 4; ++rr)
#pragma unroll
                for (int c = 0; c < 2; ++c)
                    acc[rr][c] = __builtin_amdgcn_mfma_f32_16x16x32_bf16(
                        af[rr], bf[c], acc[rr][c], 0, 0, 0);
        }
        __syncthreads();
    }

    int orow0 = by * 128 + wr * 64 + ((lane >> 4) << 2);
    int ocol0 = bx * 64 + wc * 32 + (lane & 15);
#pragma unroll
    for (int rr = 0; rr < 4; ++rr)
#pragma unroll
        for (int c = 0; c < 2; ++c)
#pragma unroll
            for (int q = 0; q < 4; ++q)
                Cb[(size_t)(orow0 + rr * 16 + q) * D_MODEL + ocol0 + c * 16] =
                    f2bf(acc[rr][c][q]);
}

// ---------------------------------------------------------------------------
// Sparse attention, two-pass, MFMA-scored. One wave (64 thr) per dst.
// (R5-measured best; R7 occupancy / R8 ILP variants were neutral-to-worse.)
// ---------------------------------------------------------------------------
__global__ __launch_bounds__(64) void attn_kernel(
        const unsigned short* __restrict__ Qb, const unsigned short* __restrict__ Kb,
        const unsigned short* __restrict__ Vb,
        const unsigned long long* __restrict__ mask,
        unsigned short* __restrict__ Ob, int n) {
    int dst = blockIdx.x;
    int L = threadIdx.x;
    int wpr = n >> 6;

    __shared__ int nbr[MAXN + 16];
    __shared__ float s_lds[N_HEADS][MAXN];

    // ---- Phase A: neighbor enumeration ----
    unsigned long long w = (L < wpr) ? mask[(size_t)dst * wpr + L] : 0ULL;
    int c = __popcll(w);
    int xs = c;
#pragma unroll
    for (int o = 1; o < 64; o <<= 1) {
        int y = __shfl_up(xs, o, 64);
        if (L >= o) xs += y;
    }
    int pos = xs - c;
    while (w) {
        int b = __builtin_ctzll(w);
        w &= w - 1;
        if (pos < MAXN) nbr[pos] = (L << 6) + b;
        ++pos;
    }
    int cnt = __shfl(xs, 63, 64);
    if (cnt > MAXN) cnt = MAXN;
    int nb = (cnt + 15) & ~15;
    __syncthreads();
    int last = nbr[cnt - 1];
    if (L < nb - cnt) nbr[cnt + L] = last;   // pad; padded scores forced to -1e30
    __syncthreads();

    // per-lane Q fragment (col = head for col<8, else zero)
    int col = L & 15;
    int kq = L >> 4;
    bf16x8 qf = (bf16x8){0, 0, 0, 0, 0, 0, 0, 0};
    if (col < N_HEADS)
        qf = *(const bf16x8*)(Qb + (size_t)dst * D_MODEL + col * 32 + kq * 8);
    const bf16x8 zf = (bf16x8){0, 0, 0, 0, 0, 0, 0, 0};
    const float inv_scale = 0.17677669529663687f;   // 1/sqrt(32)

    // ---- Phase B: scores via MFMA (head-masked B trick) ----
    for (int b0 = 0; b0 < nb; b0 += 16) {
        int nj = nbr[b0 + col];
        const unsigned short* krow = Kb + (size_t)nj * D_MODEL + kq * 8;
        f32x4 c0 = (f32x4){0.f, 0.f, 0.f, 0.f};
        f32x4 c1 = (f32x4){0.f, 0.f, 0.f, 0.f};
#pragma unroll
        for (int kb = 0; kb < 8; kb += 2) {
            bf16x8 a0 = *(const bf16x8*)(krow + kb * 32);
            bf16x8 a1 = *(const bf16x8*)(krow + kb * 32 + 32);
            bf16x8 bop0 = (col == kb)     ? qf : zf;
            bf16x8 bop1 = (col == kb + 1) ? qf : zf;
            c0 = __builtin_amdgcn_mfma_f32_16x16x32_bf16(a0, bop0, c0, 0, 0, 0);
            c1 = __builtin_amdgcn_mfma_f32_16x16x32_bf16(a1, bop1, c1, 0, 0, 0);
        }
        if (col < N_HEADS) {
            int jr = b0 + kq * 4;
            float4 o4;
            float s0 = (c0[0] + c1[0]) * inv_scale;
            float s1 = (c0[1] + c1[1]) * inv_scale;
            float s2 = (c0[2] + c1[2]) * inv_scale;
            float s3 = (c0[3] + c1[3]) * inv_scale;
            o4.x = (jr + 0 < cnt) ? s0 : -1e30f;
            o4.y = (jr + 1 < cnt) ? s1 : -1e30f;
            o4.z = (jr + 2 < cnt) ? s2 : -1e30f;
            o4.w = (jr + 3 < cnt) ? s3 : -1e30f;
            *(float4*)&s_lds[col][jr] = o4;
        }
    }
    __syncthreads();

    // ---- Phase C: softmax (h = L>>3, 8 lanes per head) ----
    int h = L >> 3, li = L & 7;
    float m = -1e30f;
    for (int j0 = li * 4; j0 < nb; j0 += 32) {
        float4 v = *(const float4*)&s_lds[h][j0];
        m = fmaxf(m, fmaxf(fmaxf(v.x, v.y), fmaxf(v.z, v.w)));
    }
    m = fmaxf(m, __shfl_xor(m, 1, 8));
    m = fmaxf(m, __shfl_xor(m, 2, 8));
    m = fmaxf(m, __shfl_xor(m, 4, 8));
    float l = 0.f;
    for (int j0 = li * 4; j0 < nb; j0 += 32) {
        float4 v = *(const float4*)&s_lds[h][j0];
        float4 e4;
        e4.x = __expf(v.x - m); e4.y = __expf(v.y - m);
        e4.z = __expf(v.z - m); e4.w = __expf(v.w - m);
        *(float4*)&s_lds[h][j0] = e4;
        l += (e4.x + e4.y) + (e4.z + e4.w);
    }
    l += __shfl_xor(l, 1, 8);
    l += __shfl_xor(l, 2, 8);
    l += __shfl_xor(l, 4, 8);
    __syncthreads();

    // ---- Phase D: PV accumulate. Lane: head h, dims (L&7)*4..+3 (offset 8L B) ----
    f32x4 acc = (f32x4){0.f, 0.f, 0.f, 0.f};
    const unsigned short* vb = Vb + 4 * L;
    for (int j = 0; j < nb; j += 4) {
        float4 wv = *(const float4*)&s_lds[h][j];
        int j0 = nbr[j], j1 = nbr[j + 1], j2 = nbr[j + 2], j3 = nbr[j + 3];
        uint2 r0 = *(const uint2*)(vb + (size_t)j0 * D_MODEL);
        uint2 r1 = *(const uint2*)(vb + (size_t)j1 * D_MODEL);
        uint2 r2 = *(const uint2*)(vb + (size_t)j2 * D_MODEL);
        uint2 r3 = *(const uint2*)(vb + (size_t)j3 * D_MODEL);
        acc[0] += wv.x * bf2f((unsigned short)(r0.x & 0xffff));
        acc[1] += wv.x * bf2f((unsigned short)(r0.x >> 16));
        acc[2] += wv.x * bf2f((unsigned short)(r0.y & 0xffff));
        acc[3] += wv.x * bf2f((unsigned short)(r0.y >> 16));
        acc[0] += wv.y * bf2f((unsigned short)(r1.x & 0xffff));
        acc[1] += wv.y * bf2f((unsigned short)(r1.x >> 16));
        acc[2] += wv.y * bf2f((unsigned short)(r1.y & 0xffff));
        acc[3] += wv.y * bf2f((unsigned short)(r1.y >> 16));
        acc[0] += wv.z * bf2f((unsigned short)(r2.x & 0xffff));
        acc[1] += wv.z * bf2f((unsigned short)(r2.x >> 16));
        acc[2] += wv.z * bf2f((unsigned short)(r2.y & 0xffff));
        acc[3] += wv.z * bf2f((unsigned short)(r2.y >> 16));
        acc[0] += wv.w * bf2f((unsigned short)(r3.x & 0xffff));
        acc[1] += wv.w * bf2f((unsigned short)(r3.x >> 16));
        acc[2] += wv.w * bf2f((unsigned short)(r3.y & 0xffff));
        acc[3] += wv.w * bf2f((unsigned short)(r3.y >> 16));
    }
    float rl = 1.f / l;
    ushort4 o;
    o.x = f2bf(acc[0] * rl); o.y = f2bf(acc[1] * rl);
    o.z = f2bf(acc[2] * rl); o.w = f2bf(acc[3] * rl);
    *(ushort4*)(Ob + (size_t)dst * D_MODEL + 4 * L) = o;
}

// ---------------------------------------------------------------------------
// Fused output GEMM + residual + bias + LayerNorm.
// BM=32, BN=256 (full row), BK=64 -> 128 blocks (R5-measured best).
// ---------------------------------------------------------------------------
struct SMemO {
    union {
        struct { short A[32][72]; short B[256][72]; } st;
        float c[32][260];
    };
};

__global__ __launch_bounds__(256) void gemm_o_ln_kernel(
        const unsigned short* __restrict__ Ob, const unsigned short* __restrict__ Wob,
        const float* __restrict__ x, const float* __restrict__ bo,
        const float* __restrict__ gamma, const float* __restrict__ beta,
        float* __restrict__ out) {
    __shared__ SMemO sm;
    int by = blockIdx.x;
    int t = threadIdx.x;
    int wave = t >> 6, lane = t & 63;
    int rt = wave >> 1, cq = wave & 1;
    int lr = t >> 3;
    int lk = (t & 7) << 3;

    const unsigned short* Abase = Ob + ((size_t)(by * 32 + lr)) * D_MODEL + lk;
    int fm = lane & 15;
    int fk = (lane >> 4) << 3;

    f32x4 acc[8];
#pragma unroll
    for (int ct = 0; ct < 8; ++ct) acc[ct] = (f32x4){0.f, 0.f, 0.f, 0.f};

    for (int k0 = 0; k0 < D_MODEL; k0 += 64) {
        *(uint4*)&sm.st.A[lr][lk] = *(const uint4*)(Abase + k0);
#pragma unroll
        for (int j = 0; j < 8; ++j)
            *(uint4*)&sm.st.B[lr + 32 * j][lk] =
                *(const uint4*)(Wob + ((size_t)(lr + 32 * j)) * D_MODEL + k0 + lk);
        __syncthreads();
#pragma unroll
        for (int ks = 0; ks < 64; ks += 32) {
            bf16x8 af = *(const bf16x8*)&sm.st.A[rt * 16 + fm][ks + fk];
#pragma unroll
            for (int ct = 0; ct < 8; ++ct) {
                bf16x8 bf = *(const bf16x8*)&sm.st.B[cq * 128 + ct * 16 + fm][ks + fk];
                acc[ct] = __builtin_amdgcn_mfma_f32_16x16x32_bf16(af, bf, acc[ct], 0, 0, 0);
            }
        }
        __syncthreads();
    }

    int rr0 = rt * 16 + ((lane >> 4) << 2);
#pragma unroll
    for (int ct = 0; ct < 8; ++ct)
#pragma unroll
        for (int q = 0; q < 4; ++q)
            sm.c[rr0 + q][cq * 128 + ct * 16 + (lane & 15)] = acc[ct][q];
    __syncthreads();

    float4 bo4 = *(const float4*)(bo + lane * 4);
    float4 g4  = *(const float4*)(gamma + lane * 4);
    float4 be4 = *(const float4*)(beta + lane * 4);
#pragma unroll
    for (int rr = 0; rr < 8; ++rr) {
        int r = wave * 8 + rr;
        int grow = by * 32 + r;
        float4 p = *(const float4*)&sm.c[r][lane * 4];
        float4 xv = *(const float4*)(x + (size_t)grow * D_MODEL + lane * 4);
        float hx = p.x + xv.x + bo4.x;
        float hy = p.y + xv.y + bo4.y;
        float hz = p.z + xv.z + bo4.z;
        float hw = p.w + xv.w + bo4.w;
        float s  = (hx + hy) + (hz + hw);
        float s2 = (hx * hx + hy * hy) + (hz * hz + hw * hw);
#pragma unroll
        for (int o = 32; o; o >>= 1) {
            s  += __shfl_xor(s, o, 64);
            s2 += __shfl_xor(s2, o, 64);
        }
        float mu = s * (1.f / 256.f);
        float var = s2 * (1.f / 256.f) - mu * mu;
        float rstd = rsqrtf(var + 1e-5f);
        float4 o4;
        o4.x = (hx - mu) * rstd * g4.x + be4.x;
        o4.y = (hy - mu) * rstd * g4.y + be4.y;
        o4.z = (hz - mu) * rstd * g4.z + be4.z;
        o4.w = (hw - mu) * rstd * g4.w + be4.w;
        *(float4*)(out + (size_t)grow * D_MODEL + lane * 4) = o4;
    }
}

// ---------------------------------------------------------------------------
extern "C" void kernel_launch(void* const* d_in, const int* in_sizes, int n_in,
                              void* d_out, int out_size, void* d_ws, size_t ws_size,
                              hipStream_t stream) {
    const float* x     = (const float*)d_in[0];
    const int*   ei    = (const int*)  d_in[1];
    const float* Wq    = (const float*)d_in[2];
    const float* Wk    = (const float*)d_in[3];
    const float* Wv    = (const float*)d_in[4];
    const float* Wo    = (const float*)d_in[5];
    const float* bo    = (const float*)d_in[6];
    const float* gamma = (const float*)d_in[7];
    const float* beta  = (const float*)d_in[8];
    float* out = (float*)d_out;

    int n = in_sizes[0] / D_MODEL;   // 4096
    int E = in_sizes[1] / 2;         // 131072

    char* ws = (char*)d_ws;
    size_t off = 0;
    unsigned long long* mask = (unsigned long long*)(ws + off);
    off += (size_t)n * (n >> 6) * sizeof(unsigned long long);          // 2 MiB
    unsigned short* xb  = (unsigned short*)(ws + off); off += (size_t)n * D_MODEL * 2;
    unsigned short* Wqb = (unsigned short*)(ws + off); off += D_MODEL * D_MODEL * 2;
    unsigned short* Wkb = (unsigned short*)(ws + off); off += D_MODEL * D_MODEL * 2;
    unsigned short* Wvb = (unsigned short*)(ws + off); off += D_MODEL * D_MODEL * 2;
    unsigned short* Wob = (unsigned short*)(ws + off); off += D_MODEL * D_MODEL * 2;
    unsigned short* Qb  = (unsigned short*)(ws + off); off += (size_t)n * D_MODEL * 2;
    unsigned short* Kb  = (unsigned short*)(ws + off); off += (size_t)n * D_MODEL * 2;
    unsigned short* Vb  = (unsigned short*)(ws + off); off += (size_t)n * D_MODEL * 2;
    unsigned short* Ob  = (unsigned short*)(ws + off); off += (size_t)n * D_MODEL * 2;

    // 1) prep: converts + mask init (diag)
    prep_kernel<<<1280, 256, 0, stream>>>(x, Wq, Wk, Wv, Wo,
                                          xb, Wqb, Wkb, Wvb, Wob, mask, n);

    // 2) fused QKV GEMM + edge scatter
    int edge_blocks = (E + 255) / 256;       // 512
    qkv_edges_kernel<<<NGEMM + edge_blocks, 256, 0, stream>>>(
        xb, Wqb, Wkb, Wvb, Qb, Kb, Vb, ei, mask, E, n);

    // 3) sparse attention: one wave per dst
    attn_kernel<<<n, 64, 0, stream>>>(Qb, Kb, Vb, mask, Ob, n);

    // 4) output GEMM + residual + LayerNorm
    gemm_o_ln_kernel<<<n / 32, 256, 0, stream>>>(Ob, Wob, x, bo, gamma, beta, out);
}